// Round 8
// baseline (151.195 us; speedup 1.0000x reference)
//
#include <hip/hip_runtime.h>

// Problem constants: N=4, C=320, H=W=D=16 -> L=4096, POS_RATIO=0.5
#define LVOX   4096
#define NCH    320
#define NCOMBO 8        // 4 batches x 2 branches (normal, batch-flipped q)
#define NSEG   64       // enum waves per combo (4096 threads / 64 lanes)
#define SEGCAP 1024     // list words per segment (hard bound: 64 l * 14 = 896)
#define PKSTR  17       // prefix-sum entries per (x,y) cell (exclusive, 0..16)
#define PKROW  (256 * PKSTR)
#define NBLK   (2 * NCH)        // gather blocks = 640
#define GOFFS  65       // goffx entries per segment (64 starts + total)
// ws layout (every consumed word deterministically written, no zeroing):
//   wpcnt [8*64] u32            @ 0
//   goffx [8*64*65] u32         @ 2048
//   Spart [8*NBLK] f32          @ 135168
//   runs  [8*64*SEGCAP] u32     @ 155648  (2 MB)
#define GOFFX_OFF 2048
#define SPART_OFF 135168
#define RUNS_OFF  155648

struct Geo {
    float qs0, qs1, qs2, qo0, qo1, qo2;
    float ks0, ks1, ks2, ko0, ko1, ko2;
    float ik0, ik1, ik2;
    float T;
};

// max_diag uses UNFLIPPED diag_q[n] even in the flipped branch (ref computes it pre-flip).
__device__ __forceinline__ Geo make_geo(const float* __restrict__ cq,
                                        const float* __restrict__ ck,
                                        int n, int qb) {
    Geo g;
    const float* qc = cq + qb * 6;
    const float* qn = cq + n * 6;
    const float* kc = ck + n * 6;
    g.qs0 = (qc[3] - qc[0]) * (1.f / 16.f); g.qo0 = qc[0];
    g.qs1 = (qc[4] - qc[1]) * (1.f / 16.f); g.qo1 = qc[1];
    g.qs2 = (qc[5] - qc[2]) * (1.f / 16.f); g.qo2 = qc[2];
    g.ks0 = (kc[3] - kc[0]) * (1.f / 16.f); g.ko0 = kc[0];
    g.ks1 = (kc[4] - kc[1]) * (1.f / 16.f); g.ko1 = kc[1];
    g.ks2 = (kc[5] - kc[2]) * (1.f / 16.f); g.ko2 = kc[2];
    g.ik0 = 1.f / g.ks0; g.ik1 = 1.f / g.ks1; g.ik2 = 1.f / g.ks2;
    float b0 = (qn[3] - qn[0]) * (1.f / 16.f);
    float b1 = (qn[4] - qn[1]) * (1.f / 16.f);
    float b2 = (qn[5] - qn[2]) * (1.f / 16.f);
    float dq = sqrtf(b0 * b0 + b1 * b1 + b2 * b2);
    float dk = sqrtf(g.ks0 * g.ks0 + g.ks1 * g.ks1 + g.ks2 * g.ks2);
    g.T = 0.5f * fmaxf(dq, dk);
    return g;
}

__device__ __forceinline__ void axrange(float c, float ko, float ik, float T,
                                        int& m0, int& m1) {
    float lo = (c - T - ko) * ik - 0.5f;
    float hi = (c + T - ko) * ik - 0.5f;
    m0 = max((int)ceilf(lo) - 1, 0);
    m1 = min((int)floorf(hi) + 1, 15);
}

// One THREAD per (combo, l). Grouped-by-l list format:
//   header = (l<<16) | nruns, then ceil(nruns/2) words of two packed runs
//   run (16b) = (cell<<8) | (zf<<4) | (len-1)
// Exact per-z sqrtf(...)<T test -> mask identical to reference.
// Wave w of combo j owns segment (j*64+w); goffx[seg][lane] = exact word
// offset of that lane's group (goffx[seg][64] = segment total). No atomics.
__global__ void enum_runs(const float* __restrict__ coord_q,
                          const float* __restrict__ coord_k,
                          unsigned* __restrict__ wpcnt,
                          unsigned* __restrict__ goffx,
                          unsigned* __restrict__ runs) {
    int gid = blockIdx.x * 256 + threadIdx.x;   // 8*4096 threads
    int j = gid >> 12;
    int l = gid & 4095;
    int seg = j * NSEG + ((gid & 4095) >> 6);   // wave-uniform
    int n = j & 3;
    int qb = (j & 4) ? (3 - n) : n;
    Geo g = make_geo(coord_q, coord_k, n, qb);

    int ix = l >> 8, iy = (l >> 4) & 15, iz = l & 15;
    float cx = (ix + 0.5f) * g.qs0 + g.qo0;
    float cy = (iy + 0.5f) * g.qs1 + g.qo1;
    float cz = (iz + 0.5f) * g.qs2 + g.qo2;
    int x0, x1, y0, y1, z0, z1;
    axrange(cx, g.ko0, g.ik0, g.T, x0, x1);
    axrange(cy, g.ko1, g.ik1, g.T, y0, y1);
    axrange(cz, g.ko2, g.ik2, g.T, z0, z1);

    // pass 1: count runs and hits
    int nh = 0, nr = 0;
    for (int x = x0; x <= x1; ++x) {
        float dx = cx - ((x + 0.5f) * g.ks0 + g.ko0);
        float dx2 = dx * dx;
        for (int y = y0; y <= y1; ++y) {
            float dy = cy - ((y + 0.5f) * g.ks1 + g.ko1);
            float dxy = dx2 + dy * dy;
            int zc = 0;
            for (int z = z0; z <= z1; ++z) {
                float dz = cz - ((z + 0.5f) * g.ks2 + g.ko2);
                if (sqrtf(dxy + dz * dz) < g.T) zc++;
            }
            if (zc) { nr++; nh += zc; }
        }
    }

    // words this group occupies: header + ceil(nr/2), or 0 if empty
    int wc = nr ? 1 + ((nr + 1) >> 1) : 0;

    // in-wave exclusive scan of word counts -> exact group offsets
    int lane = threadIdx.x & 63;
    int incl = wc;
#pragma unroll
    for (int off = 1; off < 64; off <<= 1) {
        int t = __shfl_up(incl, off, 64);
        if (lane >= off) incl += t;
    }
    int w = incl - wc;
    goffx[seg * GOFFS + lane] = (unsigned)w;
    if (lane == 63) goffx[seg * GOFFS + 64] = (unsigned)incl;

    int hsum = nh;
#pragma unroll
    for (int off = 32; off; off >>= 1) hsum += __shfl_down(hsum, off, 64);
    if (lane == 0) wpcnt[seg] = (unsigned)hsum;

    // pass 2: write header + packed runs
    if (nr) {
        unsigned* out = runs + (size_t)seg * SEGCAP;
        out[w++] = ((unsigned)l << 16) | (unsigned)nr;
        unsigned pend = 0; int have = 0;
        for (int x = x0; x <= x1; ++x) {
            float dx = cx - ((x + 0.5f) * g.ks0 + g.ko0);
            float dx2 = dx * dx;
            for (int y = y0; y <= y1; ++y) {
                float dy = cy - ((y + 0.5f) * g.ks1 + g.ko1);
                float dxy = dx2 + dy * dy;
                int zf = -1, zc = 0;
                for (int z = z0; z <= z1; ++z) {
                    float dz = cz - ((z + 0.5f) * g.ks2 + g.ko2);
                    if (sqrtf(dxy + dz * dz) < g.T) { if (!zc) zf = z; zc++; }
                }
                if (zc) {
                    unsigned r = ((unsigned)((x << 4) | y) << 8)
                               | ((unsigned)zf << 4) | (unsigned)(zc - 1);
                    if (have) { out[w++] = pend | (r << 16); have = 0; }
                    else      { pend = r; have = 1; }
                }
            }
        }
        if (have) out[w++] = pend;
    }
}

// Fused gather: one block per (group g, channel c). Group g=0 -> batches {0,3},
// g=1 -> {1,2}; combos {n0, n1, 4+n0, 4+n1} are closed over rows
// {q[n0,c], q[n1,c], k[n0,c], k[n1,c]} -> each row staged ONCE globally.
// k rows as per-(x,y)-cell exclusive z-prefix sums (stride 17): run sum =
// pk[zf+len]-pk[zf]. 8 threads per segment; q read once per GROUP (not per
// run). Per-block partials -> Spart (plain stores).
__global__ void __launch_bounds__(512) gather_fused(
        const float* __restrict__ q, const float* __restrict__ k,
        const unsigned* __restrict__ goffx, const unsigned* __restrict__ runs,
        float* __restrict__ Spart) {
    // sh layout: qa[4096] | qb[4096] | pkA[PKROW] | pkB[PKROW] | sred[32]
    __shared__ float sh[2 * LVOX + 2 * PKROW + 32];
    const int QA = 0, QB = LVOX, PK = 2 * LVOX, SR = 2 * LVOX + 2 * PKROW;

    int g = blockIdx.x;              // 0 or 1
    int c = blockIdx.y;
    int n0 = g ? 1 : 0;
    int n1 = 3 - n0;
    int t = threadIdx.x;

    // stage q rows (coalesced float4)
    const float* q0 = q + ((size_t)(n0 * NCH + c)) * LVOX;
    const float* q1 = q + ((size_t)(n1 * NCH + c)) * LVOX;
#pragma unroll
    for (int i = 0; i < 2; ++i) {
        int off = (t + 512 * i) * 4;
        *(float4*)&sh[QA + off] = *(const float4*)&q0[off];
        *(float4*)&sh[QB + off] = *(const float4*)&q1[off];
    }

    // stage k rows as exclusive z-prefix per cell: thread t owns one cell
    {
        int row = t >> 8;            // 0 -> k[n0], 1 -> k[n1]
        int cl  = t & 255;
        const float* ks = k + ((size_t)((row ? n1 : n0) * NCH + c)) * LVOX + cl * 16;
        float4 v0 = *(const float4*)&ks[0];
        float4 v1 = *(const float4*)&ks[4];
        float4 v2 = *(const float4*)&ks[8];
        float4 v3 = *(const float4*)&ks[12];
        float vv[16] = {v0.x, v0.y, v0.z, v0.w, v1.x, v1.y, v1.z, v1.w,
                        v2.x, v2.y, v2.z, v2.w, v3.x, v3.y, v3.z, v3.w};
        float* dst = &sh[PK + row * PKROW + cl * PKSTR];
        float e = 0.f;
        dst[0] = 0.f;
#pragma unroll
        for (int i = 0; i < 16; ++i) { e += vv[i]; dst[i + 1] = e; }
    }
    __syncthreads();

    const int jl[4]   = {n0, n1, 4 + n0, 4 + n1};
    const int qoff[4] = {QA, QB, QB, QA};              // combo 4+n uses q[3-n]
    const int koff[4] = {PK, PK + PKROW, PK, PK + PKROW};
    float accv[4];

    int segi = t >> 3;               // 0..63: segment within combo
    int tin  = t & 7;                // 8 threads per segment

#pragma unroll
    for (int ci = 0; ci < 4; ++ci) {
        int j = jl[ci];
        int seg = j * NSEG + segi;
        const unsigned* go = goffx + (size_t)seg * GOFFS;
        const unsigned* rl = runs + (size_t)seg * SEGCAP;
        int qb = qoff[ci], kb = koff[ci];
        float acc = 0.f;
        // thread handles groups tin, tin+8, ..., tin+56 (exact ranges via goffx)
        for (int gi = tin; gi < 64; gi += 8) {
            unsigned p  = go[gi];
            unsigned pe = go[gi + 1];
            if (p >= pe) continue;
            unsigned h = rl[p++];
            int l  = (int)((h >> 16) & 4095u);
            int nr = (int)(h & 255u);
            float qv = sh[qb + l];
            float s = 0.f;
            int nw = (nr + 1) >> 1;
            for (int wi = 0; wi < nw; ++wi) {
                unsigned rw = rl[p + wi];
                unsigned r0 = rw & 0xffffu;
                int c0 = (int)(r0 >> 8);
                int z0 = (int)((r0 >> 4) & 15u);
                int L0 = (int)(r0 & 15u) + 1;
                s += sh[kb + c0 * PKSTR + z0 + L0] - sh[kb + c0 * PKSTR + z0];
                if (2 * wi + 1 < nr) {
                    unsigned r1 = rw >> 16;
                    int c1 = (int)(r1 >> 8);
                    int z1 = (int)((r1 >> 4) & 15u);
                    int L1 = (int)(r1 & 15u) + 1;
                    s += sh[kb + c1 * PKSTR + z1 + L1] - sh[kb + c1 * PKSTR + z1];
                }
            }
            acc += qv * s;
        }
        accv[ci] = acc;
    }

    int wv = t >> 6, lane = t & 63;
#pragma unroll
    for (int ci = 0; ci < 4; ++ci) {
        float a = accv[ci];
#pragma unroll
        for (int off = 32; off; off >>= 1) a += __shfl_down(a, off, 64);
        if (lane == 0) sh[SR + wv * 4 + ci] = a;
    }
    __syncthreads();
    if (t < 4) {
        float v = 0.f;
#pragma unroll
        for (int w = 0; w < 8; ++w) v += sh[SR + w * 4 + t];
        Spart[(size_t)jl[t] * NBLK + (c * 2 + g)] = v;
    }
}

// Sum Spart over each combo's 320 written slots and wpcnt over 64 segments.
__global__ void finalize(const float* __restrict__ Spart,
                         const unsigned* __restrict__ wpcnt,
                         float* __restrict__ out) {
    __shared__ float tj[NCOMBO];
    int j = threadIdx.x >> 5;      // 8 combos x 32 threads
    int s = threadIdx.x & 31;
    int nn = j & 3;
    int gj = (nn == 1 || nn == 2) ? 1 : 0;
    float v = 0.f;
    for (int i = s; i < NCH; i += 32)
        v += Spart[(size_t)j * NBLK + i * 2 + gj];
    unsigned pc = wpcnt[j * NSEG + s] + wpcnt[j * NSEG + s + 32];
    float pcf = (float)pc;
#pragma unroll
    for (int off = 16; off; off >>= 1) {
        v   += __shfl_down(v, off, 32);
        pcf += __shfl_down(pcf, off, 32);
    }
    if (s == 0) tj[j] = v / (pcf + 1e-6f);
    __syncthreads();
    if (threadIdx.x == 0) {
        float t = 0.f;
#pragma unroll
        for (int jj = 0; jj < NCOMBO; ++jj) t += tj[jj];
        out[0] = -0.5f * t;   // -2*mean over 4 batches, x2 branches
    }
}

extern "C" void kernel_launch(void* const* d_in, const int* in_sizes, int n_in,
                              void* d_out, int out_size, void* d_ws, size_t ws_size,
                              hipStream_t stream) {
    const float* q       = (const float*)d_in[0];
    const float* k       = (const float*)d_in[1];
    const float* coord_q = (const float*)d_in[2];
    const float* coord_k = (const float*)d_in[3];
    float* out = (float*)d_out;

    unsigned* wpcnt = (unsigned*)d_ws;
    unsigned* goffx = (unsigned*)((char*)d_ws + GOFFX_OFF);
    float*    Spart = (float*)((char*)d_ws + SPART_OFF);
    unsigned* runs  = (unsigned*)((char*)d_ws + RUNS_OFF);
    // total ws use ~2.2 MB; every consumed word is written before read.

    enum_runs<<<(NCOMBO * LVOX) / 256, 256, 0, stream>>>(coord_q, coord_k, wpcnt, goffx, runs);
    gather_fused<<<dim3(2, NCH), 512, 0, stream>>>(q, k, goffx, runs, Spart);
    finalize<<<1, 256, 0, stream>>>(Spart, wpcnt, out);
}

// Round 9
// 122.580 us; speedup vs baseline: 1.2334x; 1.2334x over previous
//
#include <hip/hip_runtime.h>

// Problem constants: N=4, C=320, H=W=D=16 -> L=4096, POS_RATIO=0.5
#define LVOX   4096
#define NCH    320
#define NCOMBO 8        // 4 batches x 2 branches (normal, batch-flipped q)
#define NSEG   64       // enum waves per combo (4096 threads / 64 lanes)
#define SEGCAP 4096     // run slots per segment (worst case ~36 runs/thread * 64 = 2304)
#define PKSTR  17       // prefix-sum entries per (x,y) cell (exclusive, 0..16)
#define PKROW  (256 * PKSTR)
// ws layout (every consumed word deterministically written, no zeroing needed):
//   wcnt  [8*64] u32        @ 0
//   wpcnt [8*64] u32        @ 2048
//   Spart [8*NCH] f32       @ 4096    (one writer block per (combo, channel))
//   runs  [8*64*SEGCAP] u32 @ 16384   (8 MB)
#define WPCNT_OFF 2048
#define SPART_OFF 4096
#define RUNS_OFF  16384

struct Geo {
    float qs0, qs1, qs2, qo0, qo1, qo2;
    float ks0, ks1, ks2, ko0, ko1, ko2;
    float ik0, ik1, ik2;
    float T;
};

// max_diag uses UNFLIPPED diag_q[n] even in the flipped branch (ref computes it pre-flip).
__device__ __forceinline__ Geo make_geo(const float* __restrict__ cq,
                                        const float* __restrict__ ck,
                                        int n, int qb) {
    Geo g;
    const float* qc = cq + qb * 6;
    const float* qn = cq + n * 6;
    const float* kc = ck + n * 6;
    g.qs0 = (qc[3] - qc[0]) * (1.f / 16.f); g.qo0 = qc[0];
    g.qs1 = (qc[4] - qc[1]) * (1.f / 16.f); g.qo1 = qc[1];
    g.qs2 = (qc[5] - qc[2]) * (1.f / 16.f); g.qo2 = qc[2];
    g.ks0 = (kc[3] - kc[0]) * (1.f / 16.f); g.ko0 = kc[0];
    g.ks1 = (kc[4] - kc[1]) * (1.f / 16.f); g.ko1 = kc[1];
    g.ks2 = (kc[5] - kc[2]) * (1.f / 16.f); g.ko2 = kc[2];
    g.ik0 = 1.f / g.ks0; g.ik1 = 1.f / g.ks1; g.ik2 = 1.f / g.ks2;
    float b0 = (qn[3] - qn[0]) * (1.f / 16.f);
    float b1 = (qn[4] - qn[1]) * (1.f / 16.f);
    float b2 = (qn[5] - qn[2]) * (1.f / 16.f);
    float dq = sqrtf(b0 * b0 + b1 * b1 + b2 * b2);
    float dk = sqrtf(g.ks0 * g.ks0 + g.ks1 * g.ks1 + g.ks2 * g.ks2);
    g.T = 0.5f * fmaxf(dq, dk);
    return g;
}

__device__ __forceinline__ void axrange(float c, float ko, float ik, float T,
                                        int& m0, int& m1) {
    float lo = (c - T - ko) * ik - 0.5f;
    float hi = (c + T - ko) * ik - 0.5f;
    m0 = max((int)ceilf(lo) - 1, 0);
    m1 = min((int)floorf(hi) + 1, 15);
}

// One THREAD per (combo, l); emits one RUN per masked (x,y) cell:
//   record = (l<<16) | (m<<4) | (len-1),  m = (x<<8)|(y<<4)|z_first
// Exact per-z sqrtf(...)<T test -> mask identical to reference.
// Wave w of combo j owns segment (j*64+w): runs via in-wave prefix scan,
// counts via plain stores. NO global atomics, NO pre-zeroed memory.
__global__ void enum_runs(const float* __restrict__ coord_q,
                          const float* __restrict__ coord_k,
                          unsigned* __restrict__ wcnt,
                          unsigned* __restrict__ wpcnt,
                          unsigned* __restrict__ runs) {
    int gid = blockIdx.x * 256 + threadIdx.x;   // 8*4096 threads
    int j = gid >> 12;
    int l = gid & 4095;
    int seg = j * NSEG + ((gid & 4095) >> 6);   // wave-uniform
    int n = j & 3;
    int qb = (j & 4) ? (3 - n) : n;
    Geo g = make_geo(coord_q, coord_k, n, qb);

    int ix = l >> 8, iy = (l >> 4) & 15, iz = l & 15;
    float cx = (ix + 0.5f) * g.qs0 + g.qo0;
    float cy = (iy + 0.5f) * g.qs1 + g.qo1;
    float cz = (iz + 0.5f) * g.qs2 + g.qo2;
    int x0, x1, y0, y1, z0, z1;
    axrange(cx, g.ko0, g.ik0, g.T, x0, x1);
    axrange(cy, g.ko1, g.ik1, g.T, y0, y1);
    axrange(cz, g.ko2, g.ik2, g.T, z0, z1);

    // pass 1: count runs and hits
    int nh = 0, nr = 0;
    for (int x = x0; x <= x1; ++x) {
        float dx = cx - ((x + 0.5f) * g.ks0 + g.ko0);
        float dx2 = dx * dx;
        for (int y = y0; y <= y1; ++y) {
            float dy = cy - ((y + 0.5f) * g.ks1 + g.ko1);
            float dxy = dx2 + dy * dy;
            int zc = 0;
            for (int z = z0; z <= z1; ++z) {
                float dz = cz - ((z + 0.5f) * g.ks2 + g.ko2);
                if (sqrtf(dxy + dz * dz) < g.T) zc++;
            }
            if (zc) { nr++; nh += zc; }
        }
    }

    // in-wave exclusive position via inclusive shuffle scan
    int lane = threadIdx.x & 63;
    int incl = nr;
#pragma unroll
    for (int off = 1; off < 64; off <<= 1) {
        int t = __shfl_up(incl, off, 64);
        if (lane >= off) incl += t;
    }
    int w = incl - nr;                          // exclusive prefix within segment
    if (lane == 63) wcnt[seg] = (unsigned)incl; // total runs in segment

    int hsum = nh;
#pragma unroll
    for (int off = 32; off; off >>= 1) hsum += __shfl_down(hsum, off, 64);
    if (lane == 0) wpcnt[seg] = (unsigned)hsum; // total hits in segment

    // pass 2: write runs
    unsigned* out = runs + (size_t)seg * SEGCAP;
    for (int x = x0; x <= x1; ++x) {
        float dx = cx - ((x + 0.5f) * g.ks0 + g.ko0);
        float dx2 = dx * dx;
        for (int y = y0; y <= y1; ++y) {
            float dy = cy - ((y + 0.5f) * g.ks1 + g.ko1);
            float dxy = dx2 + dy * dy;
            int zf = -1, zc = 0;
            for (int z = z0; z <= z1; ++z) {
                float dz = cz - ((z + 0.5f) * g.ks2 + g.ko2);
                if (sqrtf(dxy + dz * dz) < g.T) { if (!zc) zf = z; zc++; }
            }
            if (zc) {
                if (w < SEGCAP)
                    out[w] = ((unsigned)l << 16)
                           | ((unsigned)((x << 8) | (y << 4) | zf) << 4)
                           | (unsigned)(zc - 1);
                w++;
            }
        }
    }
}

// Gather, q-split for occupancy: block (bx, c), bx = g*2+qi. Group g=0 ->
// batches {0,3}, g=1 -> {1,2}; the block stages ONE q row (batch qi of the
// group) + BOTH k rows as per-(x,y)-cell exclusive z-prefix sums (stride 17).
// It computes the 2 combos using that q row:
//   qi=0 -> {n0 (k[n0]), 4+n1 (k[n1])};  qi=1 -> {n1 (k[n1]), 4+n0 (k[n0])}.
// LDS = 16KB q + 34.8KB pk + red ~= 51KB -> 3 blocks/CU (vs 2 at 67KB);
// grid 4x320 = 1280 = 5*256 exact scheduling rounds. 8 threads per segment,
// uint4 = 4 independent records per iteration (R7 structure, proven fastest).
// One writer block per (combo, channel) -> plain store to Spart[j*NCH+c].
__global__ void __launch_bounds__(512) gather_fused(
        const float* __restrict__ q, const float* __restrict__ k,
        const unsigned* __restrict__ wcnt, const unsigned* __restrict__ runs,
        float* __restrict__ Spart) {
    // sh layout: qr[4096] | pkA[PKROW] | pkB[PKROW] | sred[16]
    __shared__ float sh[LVOX + 2 * PKROW + 16];
    const int QR = 0, PK = LVOX, SR = LVOX + 2 * PKROW;

    int bx = blockIdx.x;             // 0..3
    int c  = blockIdx.y;
    int g  = bx >> 1, qi = bx & 1;
    int n0 = g ? 1 : 0;
    int n1 = 3 - n0;
    int qn = qi ? n1 : n0;           // batch of the staged q row
    int t = threadIdx.x;

    // stage q row (coalesced float4): 4096 floats, 512 thr x 2 iters
    const float* qsrc = q + ((size_t)(qn * NCH + c)) * LVOX;
#pragma unroll
    for (int i = 0; i < 2; ++i) {
        int off = (t + 512 * i) * 4;
        *(float4*)&sh[QR + off] = *(const float4*)&qsrc[off];
    }

    // stage k rows as exclusive z-prefix per cell: thread t owns one cell
    {
        int row = t >> 8;            // 0 -> k[n0], 1 -> k[n1]
        int cl  = t & 255;
        const float* ks = k + ((size_t)((row ? n1 : n0) * NCH + c)) * LVOX + cl * 16;
        float4 v0 = *(const float4*)&ks[0];
        float4 v1 = *(const float4*)&ks[4];
        float4 v2 = *(const float4*)&ks[8];
        float4 v3 = *(const float4*)&ks[12];
        float vv[16] = {v0.x, v0.y, v0.z, v0.w, v1.x, v1.y, v1.z, v1.w,
                        v2.x, v2.y, v2.z, v2.w, v3.x, v3.y, v3.z, v3.w};
        float* dst = &sh[PK + row * PKROW + cl * PKSTR];
        float e = 0.f;
        dst[0] = 0.f;
#pragma unroll
        for (int i = 0; i < 16; ++i) { e += vv[i]; dst[i + 1] = e; }
    }
    __syncthreads();

    // combos for this block (see header comment)
    const int jl[2] = {qi ? n1 : n0, 4 + (qi ? n0 : n1)};
    const int kr[2] = {qi ? 1 : 0, qi ? 0 : 1};          // pk row per combo
    float accv[2];

    int segi = t >> 3;               // 0..63: segment within combo
    int tin  = t & 7;                // 8 threads per segment

#pragma unroll
    for (int ci = 0; ci < 2; ++ci) {
        int j = jl[ci];
        unsigned cnt = wcnt[j * NSEG + segi];
        if (cnt > SEGCAP) cnt = SEGCAP;
        const unsigned* rl = runs + (size_t)(j * NSEG + segi) * SEGCAP;
        int kb = PK + kr[ci] * PKROW;
        float acc = 0.f;
        for (unsigned p = (unsigned)tin * 4u; p < cnt; p += 32u) {
            uint4 r4 = *(const uint4*)&rl[p];   // p%4==0, p+3 < SEGCAP -> in-bounds
            unsigned rr[4] = {r4.x, r4.y, r4.z, r4.w};
#pragma unroll
            for (int e = 0; e < 4; ++e) {
                bool valid = (p + (unsigned)e) < cnt;
                unsigned pr = rr[e];
                int l    = (int)((pr >> 16) & 4095u);   // masked: tail-safe
                int cell = (int)((pr >> 8) & 255u);
                int zf   = (int)((pr >> 4) & 15u);
                int len  = (int)(pr & 15u) + 1;
                float s = sh[kb + cell * PKSTR + zf + len] - sh[kb + cell * PKSTR + zf];
                acc += valid ? sh[QR + l] * s : 0.f;
            }
        }
        accv[ci] = acc;
    }

    int wv = t >> 6, lane = t & 63;
#pragma unroll
    for (int ci = 0; ci < 2; ++ci) {
        float a = accv[ci];
#pragma unroll
        for (int off = 32; off; off >>= 1) a += __shfl_down(a, off, 64);
        if (lane == 0) sh[SR + wv * 2 + ci] = a;
    }
    __syncthreads();
    if (t < 2) {
        float v = 0.f;
#pragma unroll
        for (int w = 0; w < 8; ++w) v += sh[SR + w * 2 + t];
        Spart[(size_t)jl[t] * NCH + c] = v;   // unique writer per (combo, channel)
    }
}

// Sum Spart over each combo's 320 slots and wpcnt over 64 segments.
__global__ void finalize(const float* __restrict__ Spart,
                         const unsigned* __restrict__ wpcnt,
                         float* __restrict__ out) {
    __shared__ float tj[NCOMBO];
    int j = threadIdx.x >> 5;      // 8 combos x 32 threads
    int s = threadIdx.x & 31;
    float v = 0.f;
    for (int i = s; i < NCH; i += 32)
        v += Spart[(size_t)j * NCH + i];
    unsigned pc = wpcnt[j * NSEG + s] + wpcnt[j * NSEG + s + 32];
    float pcf = (float)pc;
#pragma unroll
    for (int off = 16; off; off >>= 1) {
        v   += __shfl_down(v, off, 32);
        pcf += __shfl_down(pcf, off, 32);
    }
    if (s == 0) tj[j] = v / (pcf + 1e-6f);
    __syncthreads();
    if (threadIdx.x == 0) {
        float t = 0.f;
#pragma unroll
        for (int jj = 0; jj < NCOMBO; ++jj) t += tj[jj];
        out[0] = -0.5f * t;   // -2*mean over 4 batches, x2 branches
    }
}

extern "C" void kernel_launch(void* const* d_in, const int* in_sizes, int n_in,
                              void* d_out, int out_size, void* d_ws, size_t ws_size,
                              hipStream_t stream) {
    const float* q       = (const float*)d_in[0];
    const float* k       = (const float*)d_in[1];
    const float* coord_q = (const float*)d_in[2];
    const float* coord_k = (const float*)d_in[3];
    float* out = (float*)d_out;

    unsigned* wcnt  = (unsigned*)d_ws;
    unsigned* wpcnt = (unsigned*)((char*)d_ws + WPCNT_OFF);
    float*    Spart = (float*)((char*)d_ws + SPART_OFF);
    unsigned* runs  = (unsigned*)((char*)d_ws + RUNS_OFF);
    // total ws use ~8.1 MB; every consumed word is written before read.

    enum_runs<<<(NCOMBO * LVOX) / 256, 256, 0, stream>>>(coord_q, coord_k, wcnt, wpcnt, runs);
    gather_fused<<<dim3(4, NCH), 512, 0, stream>>>(q, k, wcnt, runs, Spart);
    finalize<<<1, 256, 0, stream>>>(Spart, wpcnt, out);
}